// Round 5
// baseline (794.464 us; speedup 1.0000x reference)
//
#include <hip/hip_runtime.h>
#include <hip/hip_bf16.h>
#include <stdint.h>

#define B_ 256
#define T_ 256
#define D_ 128
#define H_ 256
#define LN_EPS 1e-5

typedef double f64x4 __attribute__((ext_vector_type(4)));

// LDS layout: [row][k] with k linear, stride 18 doubles (144 B: banks rotate by
// 4/row -> worst 2-way conflict). k-groups of 4 swizzled by (row&3) so the
// 32-B fragment read/write spreads across bank spans.
#define LSTRIDE 18
__device__ __forceinline__ int swz_off(int row, int g) { return row * LSTRIDE + ((g ^ (row & 3)) << 2); }

// Runtime probe of v_mfma_f64_16x16x4f64's C/D register->element mapping
// (verified working in round 4; probed rows feed LN grouping and C writes).
__device__ __forceinline__ bool probe_f64_mfma_layout(int l16, int lg, int* rowp)
{
  const f64x4 zz = {0.0, 0.0, 0.0, 0.0};
  const double pa_r = (lg == 0) ? (double)l16 : 0.0;  // A[i][0] = i
  const double pb_1 = (lg == 0) ? 1.0 : 0.0;          // B[0][j] = 1
  const f64x4 prow = __builtin_amdgcn_mfma_f64_16x16x4f64(pa_r, pb_1, zz, 0, 0, 0); // D[i][j]=i
  const double pa_1 = (lg == 0) ? 1.0 : 0.0;          // A[i][0] = 1
  const double pb_c = (lg == 0) ? (double)l16 : 0.0;  // B[0][j] = j
  const f64x4 pcol = __builtin_amdgcn_mfma_f64_16x16x4f64(pa_1, pb_c, zz, 0, 0, 0); // D[i][j]=j
  bool ok = true;
  int rm = 0, rp = 0;
  #pragma unroll
  for (int r = 0; r < 4; ++r) {
    const int ri = (int)prow[r];
    const int ci = (int)pcol[r];
    rowp[r] = ri;
    ok = ok && ((double)ri == prow[r]) && (ri >= 0) && (ri < 16);
    ok = ok && ((double)ci == pcol[r]) && (ci == l16);
    rm |= 1 << ri;
    rp |= ri << (4 * r);
  }
  ok = ok && (__popc(rm) == 4);
  #pragma unroll
  for (int m = 1; m <= 8; m <<= 1)
    ok = ok && (__shfl_xor(rp, m, 64) == rp);
  int rmw = rm;
  rmw |= __shfl_xor(rmw, 16, 64);
  rmw |= __shfl_xor(rmw, 32, 64);
  ok = ok && (rmw == 0xFFFF);
  return __all((int)ok) != 0;
}

// -------- K1: h1[r][h] = LN_H( x[r][:] . W1[h][:] + b1[h] ), fp64 --------
// Block 64 rows x 256 cols, 4 waves (16-row strip each), 2 blocks/CU.
// T14 split staging: global->reg early, LDS write after post-compute barrier.
__global__ __launch_bounds__(256, 2) void k1_gemm_ln(
    const float* __restrict__ x, const float* __restrict__ W1,
    const float* __restrict__ b1, const float* __restrict__ g1, const float* __restrict__ be1,
    double* __restrict__ h1, int row0)
{
  __shared__ double As[64 * LSTRIDE];    // 9.2 KB
  __shared__ double Bs[256 * LSTRIDE];   // 36.9 KB
  __shared__ int ok_sh;
  const int tid  = threadIdx.x;
  const int lane = tid & 63, wave = tid >> 6;
  const int l16  = lane & 15, lg = lane >> 4;
  const int orow = blockIdx.x * 64;
  const int grow = row0 + orow;
  const int wrow = wave * 16;

  int rowp[4];
  const bool okw = probe_f64_mfma_layout(l16, lg, rowp);
  if (tid == 0) ok_sh = 1;
  __syncthreads();
  if (lane == 0 && !okw) ok_sh = 0;
  __syncthreads();
  const bool okb = (ok_sh != 0);

  const int arow = tid >> 2, ag = tid & 3;          // A staging coords
  const float* xsrc = x + (size_t)(grow + arow) * 128 + ag * 4;
  const float* wsrc = W1 + (size_t)tid * 128;

  float4 xa, wb0, wb1, wb2, wb3;
  // prologue: stage kt=0
  xa  = *(const float4*)(xsrc);
  wb0 = *(const float4*)(wsrc + 0);
  wb1 = *(const float4*)(wsrc + 4);
  wb2 = *(const float4*)(wsrc + 8);
  wb3 = *(const float4*)(wsrc + 12);
  {
    double2* da = (double2*)&As[swz_off(arow, ag)];
    da[0] = make_double2((double)xa.x, (double)xa.y);
    da[1] = make_double2((double)xa.z, (double)xa.w);
    double2* db;
    db = (double2*)&Bs[swz_off(tid, 0)];
    db[0] = make_double2((double)wb0.x, (double)wb0.y);
    db[1] = make_double2((double)wb0.z, (double)wb0.w);
    db = (double2*)&Bs[swz_off(tid, 1)];
    db[0] = make_double2((double)wb1.x, (double)wb1.y);
    db[1] = make_double2((double)wb1.z, (double)wb1.w);
    db = (double2*)&Bs[swz_off(tid, 2)];
    db[0] = make_double2((double)wb2.x, (double)wb2.y);
    db[1] = make_double2((double)wb2.z, (double)wb2.w);
    db = (double2*)&Bs[swz_off(tid, 3)];
    db[0] = make_double2((double)wb3.x, (double)wb3.y);
    db[1] = make_double2((double)wb3.z, (double)wb3.w);
  }
  __syncthreads();

  f64x4 acc[16];
  #pragma unroll
  for (int ct = 0; ct < 16; ++ct) acc[ct] = (f64x4){0.0, 0.0, 0.0, 0.0};
  double accv[64];   // fallback accumulators (unused on MFMA path)
  if (!okb) {
    #pragma unroll
    for (int c = 0; c < 64; ++c) accv[c] = 0.0;
  }

  const int vfr = swz_off(wrow + l16, lg);          // A frag offset (row&3 == l16&3)
  for (int it = 0; it < 8; ++it) {
    // stage next tile into regs (loads in flight during compute)
    if (it < 7) {
      const int kt = (it + 1) * 16;
      xa  = *(const float4*)(xsrc + kt);
      wb0 = *(const float4*)(wsrc + kt + 0);
      wb1 = *(const float4*)(wsrc + kt + 4);
      wb2 = *(const float4*)(wsrc + kt + 8);
      wb3 = *(const float4*)(wsrc + kt + 12);
    }
    if (okb) {
      const double2* pa = (const double2*)&As[vfr];
      const double2 a01 = pa[0], a23 = pa[1];
      double aval[4] = {a01.x, a01.y, a23.x, a23.y};
      #pragma unroll
      for (int ctg = 0; ctg < 4; ++ctg) {
        double bval[4][4];
        #pragma unroll
        for (int u = 0; u < 4; ++u) {
          const int col = (ctg * 4 + u) * 16 + l16;
          const double2* pb = (const double2*)&Bs[col * LSTRIDE + ((lg ^ (l16 & 3)) << 2)];
          const double2 b01 = pb[0], b23 = pb[1];
          bval[u][0] = b01.x; bval[u][1] = b01.y; bval[u][2] = b23.x; bval[u][3] = b23.y;
        }
        #pragma unroll
        for (int ks = 0; ks < 4; ++ks)
          #pragma unroll
          for (int u = 0; u < 4; ++u)
            acc[ctg * 4 + u] = __builtin_amdgcn_mfma_f64_16x16x4f64(
                aval[ks], bval[u][ks], acc[ctg * 4 + u], 0, 0, 0);
      }
    } else {
      for (int k = 0; k < 16; ++k) {
        const int rr = wrow + l16;
        const double a = As[rr * LSTRIDE + ((((k >> 2) ^ (rr & 3)) << 2)) + (k & 3)];
        #pragma unroll
        for (int c = 0; c < 64; ++c) {
          const int col = lg * 64 + c;
          accv[c] = fma(a, Bs[col * LSTRIDE + ((((k >> 2) ^ (col & 3)) << 2)) + (k & 3)], accv[c]);
        }
      }
    }
    __syncthreads();   // all waves done reading LDS
    if (it < 7) {
      double2* da = (double2*)&As[swz_off(arow, ag)];
      da[0] = make_double2((double)xa.x, (double)xa.y);
      da[1] = make_double2((double)xa.z, (double)xa.w);
      double2* db;
      db = (double2*)&Bs[swz_off(tid, 0)];
      db[0] = make_double2((double)wb0.x, (double)wb0.y);
      db[1] = make_double2((double)wb0.z, (double)wb0.w);
      db = (double2*)&Bs[swz_off(tid, 1)];
      db[0] = make_double2((double)wb1.x, (double)wb1.y);
      db[1] = make_double2((double)wb1.z, (double)wb1.w);
      db = (double2*)&Bs[swz_off(tid, 2)];
      db[0] = make_double2((double)wb2.x, (double)wb2.y);
      db[1] = make_double2((double)wb2.z, (double)wb2.w);
      db = (double2*)&Bs[swz_off(tid, 3)];
      db[0] = make_double2((double)wb3.x, (double)wb3.y);
      db[1] = make_double2((double)wb3.z, (double)wb3.w);
    }
    __syncthreads();
  }

  if (okb) {
    double bb[16];
    #pragma unroll
    for (int ct = 0; ct < 16; ++ct) bb[ct] = (double)b1[ct * 16 + l16];
    #pragma unroll
    for (int r = 0; r < 4; ++r) {
      double s = 0.0, q = 0.0;
      #pragma unroll
      for (int ct = 0; ct < 16; ++ct) {
        const double v = acc[ct][r] + bb[ct];
        s += v; q += v * v;
      }
      s += __shfl_xor(s, 1, 64); q += __shfl_xor(q, 1, 64);
      s += __shfl_xor(s, 2, 64); q += __shfl_xor(q, 2, 64);
      s += __shfl_xor(s, 4, 64); q += __shfl_xor(q, 4, 64);
      s += __shfl_xor(s, 8, 64); q += __shfl_xor(q, 8, 64);
      const double mean = s * (1.0 / 256.0);
      const double var  = q * (1.0 / 256.0) - mean * mean;
      const double rstd = 1.0 / sqrt(var + LN_EPS);
      const int row = orow + wrow + rowp[r];
      #pragma unroll
      for (int ct = 0; ct < 16; ++ct) {
        const int col = ct * 16 + l16;
        const double v = acc[ct][r] + bb[ct];
        h1[(size_t)row * 256 + col] = (v - mean) * rstd * (double)g1[col] + (double)be1[col];
      }
    }
  } else {
    double s = 0.0, q = 0.0;
    #pragma unroll
    for (int c = 0; c < 64; ++c) {
      accv[c] += (double)b1[lg * 64 + c];
      s += accv[c]; q += accv[c] * accv[c];
    }
    s += __shfl_xor(s, 16, 64); q += __shfl_xor(q, 16, 64);
    s += __shfl_xor(s, 32, 64); q += __shfl_xor(q, 32, 64);
    const double mean = s * (1.0 / 256.0);
    const double var  = q * (1.0 / 256.0) - mean * mean;
    const double rstd = 1.0 / sqrt(var + LN_EPS);
    const int row = orow + wrow + l16;
    #pragma unroll
    for (int c = 0; c < 64; ++c) {
      const int col = lg * 64 + c;
      h1[(size_t)row * 256 + col] = (accv[c] - mean) * rstd * (double)g1[col] + (double)be1[col];
    }
  }
}

// -------- K2: LIF over T per (b,h) channel; 16-deep load batching --------
__global__ __launch_bounds__(256) void k2_lif(
    const double* __restrict__ h1, uint8_t* __restrict__ s1)
{
  const int ci = blockIdx.x * 256 + threadIdx.x;
  const int b = ci >> 8, h = ci & 255;
  const double* p = h1 + (size_t)b * (T_ * H_) + h;
  uint8_t* qp = s1 + (size_t)b * (T_ * H_) + h;
  double v = 0.0;
  for (int t0 = 0; t0 < T_; t0 += 16) {
    double xv[16];
    #pragma unroll
    for (int i = 0; i < 16; ++i) xv[i] = p[(size_t)(t0 + i) * H_];
    #pragma unroll
    for (int i = 0; i < 16; ++i) {
      const double hm = v + (xv[i] - v) * 0.5;
      const bool s = (hm >= 1.0);
      v = s ? 0.0 : hm;
      qp[(size_t)(t0 + i) * H_] = s ? (uint8_t)1 : (uint8_t)0;
    }
  }
}

// -------- K3: h2[r][d] = LN_D( s1[r][:] . W2[d][:] + b2[d] ), fp64 --------
// Block 64 rows x 128 cols, 4 waves; same structure as K1, NT=16 k-tiles.
__global__ __launch_bounds__(256, 2) void k3_gemm_ln(
    const uint8_t* __restrict__ s1, const float* __restrict__ W2,
    const float* __restrict__ b2, const float* __restrict__ g2, const float* __restrict__ be2,
    double* __restrict__ h2)
{
  __shared__ double As[64 * LSTRIDE];    // 9.2 KB
  __shared__ double Bs[128 * LSTRIDE];   // 18.4 KB
  __shared__ int ok_sh;
  const int tid  = threadIdx.x;
  const int lane = tid & 63, wave = tid >> 6;
  const int l16  = lane & 15, lg = lane >> 4;
  const int orow = blockIdx.x * 64;
  const int wrow = wave * 16;

  int rowp[4];
  const bool okw = probe_f64_mfma_layout(l16, lg, rowp);
  if (tid == 0) ok_sh = 1;
  __syncthreads();
  if (lane == 0 && !okw) ok_sh = 0;
  __syncthreads();
  const bool okb = (ok_sh != 0);

  const int arow = tid >> 2, ag = tid & 3;
  const int bcol = tid >> 1, bhalf = tid & 1;       // B staging: 2 float4 per thread
  const uint8_t* asrc = s1 + (size_t)(orow + arow) * 256 + ag * 4;
  const float* wsrc = W2 + (size_t)bcol * 256 + bhalf * 8;

  uint32_t ua;
  float4 wb0, wb1;
  ua  = *(const uint32_t*)(asrc);
  wb0 = *(const float4*)(wsrc + 0);
  wb1 = *(const float4*)(wsrc + 4);
  {
    double2* da = (double2*)&As[swz_off(arow, ag)];
    da[0] = make_double2((double)(ua & 0xffu), (double)((ua >> 8) & 0xffu));
    da[1] = make_double2((double)((ua >> 16) & 0xffu), (double)((ua >> 24) & 0xffu));
    double2* db;
    db = (double2*)&Bs[swz_off(bcol, bhalf * 2 + 0)];
    db[0] = make_double2((double)wb0.x, (double)wb0.y);
    db[1] = make_double2((double)wb0.z, (double)wb0.w);
    db = (double2*)&Bs[swz_off(bcol, bhalf * 2 + 1)];
    db[0] = make_double2((double)wb1.x, (double)wb1.y);
    db[1] = make_double2((double)wb1.z, (double)wb1.w);
  }
  __syncthreads();

  f64x4 acc[8];
  #pragma unroll
  for (int ct = 0; ct < 8; ++ct) acc[ct] = (f64x4){0.0, 0.0, 0.0, 0.0};
  double accv[32];
  if (!okb) {
    #pragma unroll
    for (int c = 0; c < 32; ++c) accv[c] = 0.0;
  }

  const int vfr = swz_off(wrow + l16, lg);
  for (int it = 0; it < 16; ++it) {
    if (it < 15) {
      const int kt = (it + 1) * 16;
      ua  = *(const uint32_t*)(asrc + kt);
      wb0 = *(const float4*)(wsrc + kt + 0);
      wb1 = *(const float4*)(wsrc + kt + 4);
    }
    if (okb) {
      const double2* pa = (const double2*)&As[vfr];
      const double2 a01 = pa[0], a23 = pa[1];
      double aval[4] = {a01.x, a01.y, a23.x, a23.y};
      #pragma unroll
      for (int ctg = 0; ctg < 2; ++ctg) {
        double bval[4][4];
        #pragma unroll
        for (int u = 0; u < 4; ++u) {
          const int col = (ctg * 4 + u) * 16 + l16;
          const double2* pb = (const double2*)&Bs[col * LSTRIDE + ((lg ^ (l16 & 3)) << 2)];
          const double2 b01 = pb[0], b23 = pb[1];
          bval[u][0] = b01.x; bval[u][1] = b01.y; bval[u][2] = b23.x; bval[u][3] = b23.y;
        }
        #pragma unroll
        for (int ks = 0; ks < 4; ++ks)
          #pragma unroll
          for (int u = 0; u < 4; ++u)
            acc[ctg * 4 + u] = __builtin_amdgcn_mfma_f64_16x16x4f64(
                aval[ks], bval[u][ks], acc[ctg * 4 + u], 0, 0, 0);
      }
    } else {
      for (int k = 0; k < 16; ++k) {
        const int rr = wrow + l16;
        const double a = As[rr * LSTRIDE + ((((k >> 2) ^ (rr & 3)) << 2)) + (k & 3)];
        #pragma unroll
        for (int c = 0; c < 32; ++c) {
          const int col = lg * 32 + c;
          accv[c] = fma(a, Bs[col * LSTRIDE + ((((k >> 2) ^ (col & 3)) << 2)) + (k & 3)], accv[c]);
        }
      }
    }
    __syncthreads();
    if (it < 15) {
      double2* da = (double2*)&As[swz_off(arow, ag)];
      da[0] = make_double2((double)(ua & 0xffu), (double)((ua >> 8) & 0xffu));
      da[1] = make_double2((double)((ua >> 16) & 0xffu), (double)((ua >> 24) & 0xffu));
      double2* db;
      db = (double2*)&Bs[swz_off(bcol, bhalf * 2 + 0)];
      db[0] = make_double2((double)wb0.x, (double)wb0.y);
      db[1] = make_double2((double)wb0.z, (double)wb0.w);
      db = (double2*)&Bs[swz_off(bcol, bhalf * 2 + 1)];
      db[0] = make_double2((double)wb1.x, (double)wb1.y);
      db[1] = make_double2((double)wb1.z, (double)wb1.w);
    }
    __syncthreads();
  }

  if (okb) {
    double bb[8];
    #pragma unroll
    for (int ct = 0; ct < 8; ++ct) bb[ct] = (double)b2[ct * 16 + l16];
    #pragma unroll
    for (int r = 0; r < 4; ++r) {
      double s = 0.0, q = 0.0;
      #pragma unroll
      for (int ct = 0; ct < 8; ++ct) {
        const double v = acc[ct][r] + bb[ct];
        s += v; q += v * v;
      }
      s += __shfl_xor(s, 1, 64); q += __shfl_xor(q, 1, 64);
      s += __shfl_xor(s, 2, 64); q += __shfl_xor(q, 2, 64);
      s += __shfl_xor(s, 4, 64); q += __shfl_xor(q, 4, 64);
      s += __shfl_xor(s, 8, 64); q += __shfl_xor(q, 8, 64);
      const double mean = s * (1.0 / 128.0);
      const double var  = q * (1.0 / 128.0) - mean * mean;
      const double rstd = 1.0 / sqrt(var + LN_EPS);
      const int row = orow + wrow + rowp[r];
      #pragma unroll
      for (int ct = 0; ct < 8; ++ct) {
        const int col = ct * 16 + l16;
        const double v = acc[ct][r] + bb[ct];
        h2[(size_t)row * 128 + col] = (v - mean) * rstd * (double)g2[col] + (double)be2[col];
      }
    }
  } else {
    double s = 0.0, q = 0.0;
    #pragma unroll
    for (int c = 0; c < 32; ++c) {
      accv[c] += (double)b2[lg * 32 + c];
      s += accv[c]; q += accv[c] * accv[c];
    }
    s += __shfl_xor(s, 16, 64); q += __shfl_xor(q, 16, 64);
    s += __shfl_xor(s, 32, 64); q += __shfl_xor(q, 32, 64);
    const double mean = s * (1.0 / 128.0);
    const double var  = q * (1.0 / 128.0) - mean * mean;
    const double rstd = 1.0 / sqrt(var + LN_EPS);
    const int row = orow + wrow + l16;
    #pragma unroll
    for (int c = 0; c < 32; ++c) {
      const int col = lg * 32 + c;
      h2[(size_t)row * 128 + col] = (accv[c] - mean) * rstd * (double)g2[col] + (double)be2[col];
    }
  }
}

// -------- K4: LIF over T per (b,d) + residual add; 16-deep batching --------
__global__ __launch_bounds__(256) void k4_lif_res(
    const double* __restrict__ h2, const float* __restrict__ x,
    float* __restrict__ out, int row0, int nch)
{
  const int ci = blockIdx.x * 256 + threadIdx.x;
  if (ci >= nch) return;
  const int b = ci >> 7, d = ci & 127;
  const double* p = h2 + (size_t)b * (T_ * D_) + d;
  const size_t gbase = ((size_t)row0 + (size_t)b * T_) * D_ + d;
  double v = 0.0;
  for (int t0 = 0; t0 < T_; t0 += 16) {
    double hv[16];
    float xr[16];
    #pragma unroll
    for (int i = 0; i < 16; ++i) hv[i] = p[(size_t)(t0 + i) * D_];
    #pragma unroll
    for (int i = 0; i < 16; ++i) xr[i] = x[gbase + (size_t)(t0 + i) * D_];
    #pragma unroll
    for (int i = 0; i < 16; ++i) {
      const double hm = v + (hv[i] - v) * 0.5;
      const bool s = (hm >= 1.0);
      v = s ? 0.0 : hm;
      out[gbase + (size_t)(t0 + i) * D_] = xr[i] + (s ? 1.0f : 0.0f);
    }
  }
}

extern "C" void kernel_launch(void* const* d_in, const int* in_sizes, int n_in,
                              void* d_out, int out_size, void* d_ws, size_t ws_size,
                              hipStream_t stream)
{
  const float* x   = (const float*)d_in[0];
  const float* W1  = (const float*)d_in[1];
  const float* b1  = (const float*)d_in[2];
  const float* g1  = (const float*)d_in[3];
  const float* be1 = (const float*)d_in[4];
  const float* W2  = (const float*)d_in[5];
  const float* b2  = (const float*)d_in[6];
  const float* g2  = (const float*)d_in[7];
  const float* be2 = (const float*)d_in[8];
  float* out = (float*)d_out;

  const size_t per_b = (size_t)T_*H_*sizeof(double) + (size_t)T_*H_ + (size_t)T_*D_*sizeof(double);
  int Bc = B_;
  while (Bc > 1 && (size_t)Bc * per_b > ws_size) Bc >>= 1;

  double*  h1 = (double*)d_ws;
  uint8_t* s1 = (uint8_t*)d_ws + (size_t)Bc*T_*H_*sizeof(double);
  double*  h2 = (double*)((uint8_t*)d_ws + (size_t)Bc*T_*H_*sizeof(double) + (size_t)Bc*T_*H_);

  const int nchunk = B_ / Bc;
  const int nch4 = Bc * D_;                       // k4 channels per chunk
  const int g4 = (nch4 + 255) / 256;
  for (int c = 0; c < nchunk; ++c) {
    const int row0 = c * Bc * T_;
    k1_gemm_ln<<<dim3(Bc*4), dim3(256), 0, stream>>>(x, W1, b1, g1, be1, h1, row0);
    k2_lif   <<<dim3(Bc),   dim3(256), 0, stream>>>(h1, s1);
    k3_gemm_ln<<<dim3(Bc*4), dim3(256), 0, stream>>>(s1, W2, b2, g2, be2, h2);
    k4_lif_res<<<dim3(g4),  dim3(256), 0, stream>>>(h2, x, out, row0, nch4);
  }
}

// Round 6
// 308.689 us; speedup vs baseline: 2.5737x; 2.5737x over previous
//
#include <hip/hip_runtime.h>
#include <hip/hip_bf16.h>
#include <stdint.h>

#define B_ 256
#define T_ 256
#define D_ 128
#define H_ 256
#define LN_EPS 1e-5

typedef double f64x4 __attribute__((ext_vector_type(4)));

// LDS layout: [row][k] with k linear, stride 18 doubles (144 B: banks rotate by
// 4/row -> worst 2-way conflict). k-groups of 4 swizzled by (row&3).
#define LSTRIDE 18
__device__ __forceinline__ int swz_off(int row, int g) { return row * LSTRIDE + ((g ^ (row & 3)) << 2); }

// Probe v_mfma_f64_16x16x4f64's C/D register->row mapping (validated on this
// chip in rounds 4/5; kept because it is ~free and makes the C-write correct
// under any group-uniform mapping). A: lane l holds A[l&15][l>>4];
// B: lane l holds B[l>>4][l&15]; D col = l&15, row = rowp[reg].
__device__ __forceinline__ void probe_f64_mfma_rows(int l16, int lg, int* rowp)
{
  const f64x4 zz = {0.0, 0.0, 0.0, 0.0};
  const double pa_r = (lg == 0) ? (double)l16 : 0.0;  // A[i][0] = i
  const double pb_1 = (lg == 0) ? 1.0 : 0.0;          // B[0][j] = 1
  const f64x4 prow = __builtin_amdgcn_mfma_f64_16x16x4f64(pa_r, pb_1, zz, 0, 0, 0); // D[i][j]=i
  #pragma unroll
  for (int r = 0; r < 4; ++r) rowp[r] = (int)prow[r];
}

// -------- K1: h1[r][h] = LN_H( x[r][:] . W1[h][:] + b1[h] ), fp64 MFMA ------
// Block 64 rows x 256 cols, 4 waves (16-row strip each), 2 blocks/CU.
// T14 split staging: global->reg issued before compute, LDS write after the
// post-compute barrier (HBM latency hides under ~4096 cyc of MFMA).
__global__ __launch_bounds__(256, 2) void k1_gemm_ln(
    const float* __restrict__ x, const float* __restrict__ W1,
    const float* __restrict__ b1, const float* __restrict__ g1, const float* __restrict__ be1,
    double* __restrict__ h1, int row0)
{
  __shared__ double As[64 * LSTRIDE];    // 9.2 KB
  __shared__ double Bs[256 * LSTRIDE];   // 36.9 KB
  const int tid  = threadIdx.x;
  const int lane = tid & 63, wave = tid >> 6;
  const int l16  = lane & 15, lg = lane >> 4;
  const int orow = blockIdx.x * 64;
  const int grow = row0 + orow;
  const int wrow = wave * 16;

  int rowp[4];
  probe_f64_mfma_rows(l16, lg, rowp);

  const int arow = tid >> 2, ag = tid & 3;          // A staging coords
  const float* xsrc = x + (size_t)(grow + arow) * 128 + ag * 4;
  const float* wsrc = W1 + (size_t)tid * 128;

  float4 xa, wb0, wb1, wb2, wb3;
  // prologue: stage kt=0
  xa  = *(const float4*)(xsrc);
  wb0 = *(const float4*)(wsrc + 0);
  wb1 = *(const float4*)(wsrc + 4);
  wb2 = *(const float4*)(wsrc + 8);
  wb3 = *(const float4*)(wsrc + 12);
  {
    double2* da = (double2*)&As[swz_off(arow, ag)];
    da[0] = make_double2((double)xa.x, (double)xa.y);
    da[1] = make_double2((double)xa.z, (double)xa.w);
    double2* db;
    db = (double2*)&Bs[swz_off(tid, 0)];
    db[0] = make_double2((double)wb0.x, (double)wb0.y);
    db[1] = make_double2((double)wb0.z, (double)wb0.w);
    db = (double2*)&Bs[swz_off(tid, 1)];
    db[0] = make_double2((double)wb1.x, (double)wb1.y);
    db[1] = make_double2((double)wb1.z, (double)wb1.w);
    db = (double2*)&Bs[swz_off(tid, 2)];
    db[0] = make_double2((double)wb2.x, (double)wb2.y);
    db[1] = make_double2((double)wb2.z, (double)wb2.w);
    db = (double2*)&Bs[swz_off(tid, 3)];
    db[0] = make_double2((double)wb3.x, (double)wb3.y);
    db[1] = make_double2((double)wb3.z, (double)wb3.w);
  }
  __syncthreads();

  f64x4 acc[16];
  #pragma unroll
  for (int ct = 0; ct < 16; ++ct) acc[ct] = (f64x4){0.0, 0.0, 0.0, 0.0};

  const int vfr = swz_off(wrow + l16, lg);          // A frag offset
  for (int it = 0; it < 8; ++it) {
    if (it < 7) {   // issue next tile's global loads (in flight during MFMA)
      const int kt = (it + 1) * 16;
      xa  = *(const float4*)(xsrc + kt);
      wb0 = *(const float4*)(wsrc + kt + 0);
      wb1 = *(const float4*)(wsrc + kt + 4);
      wb2 = *(const float4*)(wsrc + kt + 8);
      wb3 = *(const float4*)(wsrc + kt + 12);
    }
    {
      const double2* pa = (const double2*)&As[vfr];
      const double2 a01 = pa[0], a23 = pa[1];
      double aval[4] = {a01.x, a01.y, a23.x, a23.y};
      #pragma unroll
      for (int ctg = 0; ctg < 4; ++ctg) {
        double bval[4][4];
        #pragma unroll
        for (int u = 0; u < 4; ++u) {
          const int col = (ctg * 4 + u) * 16 + l16;
          const double2* pb = (const double2*)&Bs[col * LSTRIDE + ((lg ^ (l16 & 3)) << 2)];
          const double2 b01 = pb[0], b23 = pb[1];
          bval[u][0] = b01.x; bval[u][1] = b01.y; bval[u][2] = b23.x; bval[u][3] = b23.y;
        }
        #pragma unroll
        for (int ks = 0; ks < 4; ++ks)
          #pragma unroll
          for (int u = 0; u < 4; ++u)
            acc[ctg * 4 + u] = __builtin_amdgcn_mfma_f64_16x16x4f64(
                aval[ks], bval[u][ks], acc[ctg * 4 + u], 0, 0, 0);
      }
    }
    __syncthreads();   // all waves done reading LDS
    if (it < 7) {
      double2* da = (double2*)&As[swz_off(arow, ag)];
      da[0] = make_double2((double)xa.x, (double)xa.y);
      da[1] = make_double2((double)xa.z, (double)xa.w);
      double2* db;
      db = (double2*)&Bs[swz_off(tid, 0)];
      db[0] = make_double2((double)wb0.x, (double)wb0.y);
      db[1] = make_double2((double)wb0.z, (double)wb0.w);
      db = (double2*)&Bs[swz_off(tid, 1)];
      db[0] = make_double2((double)wb1.x, (double)wb1.y);
      db[1] = make_double2((double)wb1.z, (double)wb1.w);
      db = (double2*)&Bs[swz_off(tid, 2)];
      db[0] = make_double2((double)wb2.x, (double)wb2.y);
      db[1] = make_double2((double)wb2.z, (double)wb2.w);
      db = (double2*)&Bs[swz_off(tid, 3)];
      db[0] = make_double2((double)wb3.x, (double)wb3.y);
      db[1] = make_double2((double)wb3.z, (double)wb3.w);
    }
    __syncthreads();
  }

  double bb[16];
  #pragma unroll
  for (int ct = 0; ct < 16; ++ct) bb[ct] = (double)b1[ct * 16 + l16];
  #pragma unroll
  for (int r = 0; r < 4; ++r) {
    double s = 0.0, q = 0.0;
    #pragma unroll
    for (int ct = 0; ct < 16; ++ct) {
      const double v = acc[ct][r] + bb[ct];
      s += v; q += v * v;
    }
    s += __shfl_xor(s, 1, 64); q += __shfl_xor(q, 1, 64);
    s += __shfl_xor(s, 2, 64); q += __shfl_xor(q, 2, 64);
    s += __shfl_xor(s, 4, 64); q += __shfl_xor(q, 4, 64);
    s += __shfl_xor(s, 8, 64); q += __shfl_xor(q, 8, 64);
    const double mean = s * (1.0 / 256.0);
    const double var  = q * (1.0 / 256.0) - mean * mean;
    const double rstd = 1.0 / sqrt(var + LN_EPS);
    const int row = orow + wrow + rowp[r];
    #pragma unroll
    for (int ct = 0; ct < 16; ++ct) {
      const int col = ct * 16 + l16;
      const double v = acc[ct][r] + bb[ct];
      h1[(size_t)row * 256 + col] = (v - mean) * rstd * (double)g1[col] + (double)be1[col];
    }
  }
}

// -------- K2: LIF over T per (b,h) channel; 16-deep load batching --------
__global__ __launch_bounds__(256) void k2_lif(
    const double* __restrict__ h1, uint8_t* __restrict__ s1)
{
  const int ci = blockIdx.x * 256 + threadIdx.x;
  const int b = ci >> 8, h = ci & 255;
  const double* p = h1 + (size_t)b * (T_ * H_) + h;
  uint8_t* qp = s1 + (size_t)b * (T_ * H_) + h;
  double v = 0.0;
  for (int t0 = 0; t0 < T_; t0 += 16) {
    double xv[16];
    #pragma unroll
    for (int i = 0; i < 16; ++i) xv[i] = p[(size_t)(t0 + i) * H_];
    #pragma unroll
    for (int i = 0; i < 16; ++i) {
      const double hm = v + (xv[i] - v) * 0.5;
      const bool s = (hm >= 1.0);
      v = s ? 0.0 : hm;
      qp[(size_t)(t0 + i) * H_] = s ? (uint8_t)1 : (uint8_t)0;
    }
  }
}

// -------- K3: h2[r][d] = LN_D( s1[r][:] . W2[d][:] + b2[d] ), fp64 MFMA -----
// Block 64 rows x 128 cols, 4 waves; same structure as K1, 16 k-tiles.
__global__ __launch_bounds__(256, 2) void k3_gemm_ln(
    const uint8_t* __restrict__ s1, const float* __restrict__ W2,
    const float* __restrict__ b2, const float* __restrict__ g2, const float* __restrict__ be2,
    double* __restrict__ h2)
{
  __shared__ double As[64 * LSTRIDE];    // 9.2 KB
  __shared__ double Bs[128 * LSTRIDE];   // 18.4 KB
  const int tid  = threadIdx.x;
  const int lane = tid & 63, wave = tid >> 6;
  const int l16  = lane & 15, lg = lane >> 4;
  const int orow = blockIdx.x * 64;
  const int wrow = wave * 16;

  int rowp[4];
  probe_f64_mfma_rows(l16, lg, rowp);

  const int arow = tid >> 2, ag = tid & 3;
  const int bcol = tid >> 1, bhalf = tid & 1;       // B staging: 2 float4/thread
  const uint8_t* asrc = s1 + (size_t)(orow + arow) * 256 + ag * 4;
  const float* wsrc = W2 + (size_t)bcol * 256 + bhalf * 8;

  uint32_t ua;
  float4 wb0, wb1;
  ua  = *(const uint32_t*)(asrc);
  wb0 = *(const float4*)(wsrc + 0);
  wb1 = *(const float4*)(wsrc + 4);
  {
    double2* da = (double2*)&As[swz_off(arow, ag)];
    da[0] = make_double2((double)(ua & 0xffu), (double)((ua >> 8) & 0xffu));
    da[1] = make_double2((double)((ua >> 16) & 0xffu), (double)((ua >> 24) & 0xffu));
    double2* db;
    db = (double2*)&Bs[swz_off(bcol, bhalf * 2 + 0)];
    db[0] = make_double2((double)wb0.x, (double)wb0.y);
    db[1] = make_double2((double)wb0.z, (double)wb0.w);
    db = (double2*)&Bs[swz_off(bcol, bhalf * 2 + 1)];
    db[0] = make_double2((double)wb1.x, (double)wb1.y);
    db[1] = make_double2((double)wb1.z, (double)wb1.w);
  }
  __syncthreads();

  f64x4 acc[8];
  #pragma unroll
  for (int ct = 0; ct < 8; ++ct) acc[ct] = (f64x4){0.0, 0.0, 0.0, 0.0};

  const int vfr = swz_off(wrow + l16, lg);
  for (int it = 0; it < 16; ++it) {
    if (it < 15) {
      const int kt = (it + 1) * 16;
      ua  = *(const uint32_t*)(asrc + kt);
      wb0 = *(const float4*)(wsrc + kt + 0);
      wb1 = *(const float4*)(wsrc + kt + 4);
    }
    {
      const double2* pa = (const double2*)&As[vfr];
      const double2 a01 = pa[0], a23 = pa[1];
      double aval[4] = {a01.x, a01.y, a23.x, a23.y};
      #pragma unroll
      for (int ctg = 0; ctg < 2; ++ctg) {
        double bval[4][4];
        #pragma unroll
        for (int u = 0; u < 4; ++u) {
          const int col = (ctg * 4 + u) * 16 + l16;
          const double2* pb = (const double2*)&Bs[col * LSTRIDE + ((lg ^ (l16 & 3)) << 2)];
          const double2 b01 = pb[0], b23 = pb[1];
          bval[u][0] = b01.x; bval[u][1] = b01.y; bval[u][2] = b23.x; bval[u][3] = b23.y;
        }
        #pragma unroll
        for (int ks = 0; ks < 4; ++ks)
          #pragma unroll
          for (int u = 0; u < 4; ++u)
            acc[ctg * 4 + u] = __builtin_amdgcn_mfma_f64_16x16x4f64(
                aval[ks], bval[u][ks], acc[ctg * 4 + u], 0, 0, 0);
      }
    }
    __syncthreads();
    if (it < 15) {
      double2* da = (double2*)&As[swz_off(arow, ag)];
      da[0] = make_double2((double)(ua & 0xffu), (double)((ua >> 8) & 0xffu));
      da[1] = make_double2((double)((ua >> 16) & 0xffu), (double)((ua >> 24) & 0xffu));
      double2* db;
      db = (double2*)&Bs[swz_off(bcol, bhalf * 2 + 0)];
      db[0] = make_double2((double)wb0.x, (double)wb0.y);
      db[1] = make_double2((double)wb0.z, (double)wb0.w);
      db = (double2*)&Bs[swz_off(bcol, bhalf * 2 + 1)];
      db[0] = make_double2((double)wb1.x, (double)wb1.y);
      db[1] = make_double2((double)wb1.z, (double)wb1.w);
    }
    __syncthreads();
  }

  double bb[8];
  #pragma unroll
  for (int ct = 0; ct < 8; ++ct) bb[ct] = (double)b2[ct * 16 + l16];
  #pragma unroll
  for (int r = 0; r < 4; ++r) {
    double s = 0.0, q = 0.0;
    #pragma unroll
    for (int ct = 0; ct < 8; ++ct) {
      const double v = acc[ct][r] + bb[ct];
      s += v; q += v * v;
    }
    s += __shfl_xor(s, 1, 64); q += __shfl_xor(q, 1, 64);
    s += __shfl_xor(s, 2, 64); q += __shfl_xor(q, 2, 64);
    s += __shfl_xor(s, 4, 64); q += __shfl_xor(q, 4, 64);
    s += __shfl_xor(s, 8, 64); q += __shfl_xor(q, 8, 64);
    const double mean = s * (1.0 / 128.0);
    const double var  = q * (1.0 / 128.0) - mean * mean;
    const double rstd = 1.0 / sqrt(var + LN_EPS);
    const int row = orow + wrow + rowp[r];
    #pragma unroll
    for (int ct = 0; ct < 8; ++ct) {
      const int col = ct * 16 + l16;
      const double v = acc[ct][r] + bb[ct];
      h2[(size_t)row * 128 + col] = (v - mean) * rstd * (double)g2[col] + (double)be2[col];
    }
  }
}

// -------- K4: LIF over T per (b,d) + residual add; 16-deep batching --------
__global__ __launch_bounds__(256) void k4_lif_res(
    const double* __restrict__ h2, const float* __restrict__ x,
    float* __restrict__ out, int row0, int nch)
{
  const int ci = blockIdx.x * 256 + threadIdx.x;
  if (ci >= nch) return;
  const int b = ci >> 7, d = ci & 127;
  const double* p = h2 + (size_t)b * (T_ * D_) + d;
  const size_t gbase = ((size_t)row0 + (size_t)b * T_) * D_ + d;
  double v = 0.0;
  for (int t0 = 0; t0 < T_; t0 += 16) {
    double hv[16];
    float xr[16];
    #pragma unroll
    for (int i = 0; i < 16; ++i) hv[i] = p[(size_t)(t0 + i) * D_];
    #pragma unroll
    for (int i = 0; i < 16; ++i) xr[i] = x[gbase + (size_t)(t0 + i) * D_];
    #pragma unroll
    for (int i = 0; i < 16; ++i) {
      const double hm = v + (hv[i] - v) * 0.5;
      const bool s = (hm >= 1.0);
      v = s ? 0.0 : hm;
      out[gbase + (size_t)(t0 + i) * D_] = xr[i] + (s ? 1.0f : 0.0f);
    }
  }
}

extern "C" void kernel_launch(void* const* d_in, const int* in_sizes, int n_in,
                              void* d_out, int out_size, void* d_ws, size_t ws_size,
                              hipStream_t stream)
{
  const float* x   = (const float*)d_in[0];
  const float* W1  = (const float*)d_in[1];
  const float* b1  = (const float*)d_in[2];
  const float* g1  = (const float*)d_in[3];
  const float* be1 = (const float*)d_in[4];
  const float* W2  = (const float*)d_in[5];
  const float* b2  = (const float*)d_in[6];
  const float* g2  = (const float*)d_in[7];
  const float* be2 = (const float*)d_in[8];
  float* out = (float*)d_out;

  const size_t per_b = (size_t)T_*H_*sizeof(double) + (size_t)T_*H_ + (size_t)T_*D_*sizeof(double);
  int Bc = B_;
  while (Bc > 1 && (size_t)Bc * per_b > ws_size) Bc >>= 1;

  double*  h1 = (double*)d_ws;
  uint8_t* s1 = (uint8_t*)d_ws + (size_t)Bc*T_*H_*sizeof(double);
  double*  h2 = (double*)((uint8_t*)d_ws + (size_t)Bc*T_*H_*sizeof(double) + (size_t)Bc*T_*H_);

  const int nchunk = B_ / Bc;
  const int nch4 = Bc * D_;
  const int g4 = (nch4 + 255) / 256;
  for (int c = 0; c < nchunk; ++c) {
    const int row0 = c * Bc * T_;
    k1_gemm_ln<<<dim3(Bc*4), dim3(256), 0, stream>>>(x, W1, b1, g1, be1, h1, row0);
    k2_lif   <<<dim3(Bc),   dim3(256), 0, stream>>>(h1, s1);
    k3_gemm_ln<<<dim3(Bc*4), dim3(256), 0, stream>>>(s1, W2, b2, g2, be2, h2);
    k4_lif_res<<<dim3(g4),  dim3(256), 0, stream>>>(h2, x, out, row0, nch4);
  }
}